// Round 14
// baseline (194.935 us; speedup 1.0000x reference)
//
#include <hip/hip_runtime.h>
#include <stdint.h>

#define NN 100000
#define NE 1000000
#define HID 128
#define NB 391            // ceil(NN/256) buckets of 256 nodes

typedef __attribute__((ext_vector_type(4))) float f32x4;
typedef __attribute__((ext_vector_type(4))) unsigned u32x4;
typedef __attribute__((ext_vector_type(8))) short short8;
typedef __attribute__((ext_vector_type(8))) __bf16 bf16x8;

union V8 { short8 s; bf16x8 b; };
union AW { unsigned w[4]; bf16x8 b; };
union BP { struct { unsigned long long lo, hi; } u; short8 s; bf16x8 b; };

__device__ __forceinline__ unsigned short f2bf(float f) {
    unsigned u = __float_as_uint(f);
    unsigned r = u + 0x7fffu + ((u >> 16) & 1u);
    return (unsigned short)(r >> 16);
}

// ---- fused prep: cast | prepw | evec | zero-row | bincount, by blockIdx ----
__global__ __launch_bounds__(256) void k_prep(
        const float* __restrict__ n_feat, unsigned* __restrict__ nfbf_u,
        const float* __restrict__ WI, const float* __restrict__ WO,
        const float* __restrict__ WS, const float* __restrict__ bI,
        const float* __restrict__ bO, const float* __restrict__ bS,
        unsigned short* __restrict__ Wbf, float* __restrict__ biasc,
        const float* __restrict__ W_rel, const float* __restrict__ b_rel,
        const float* __restrict__ e_fwd, const float* __restrict__ e_rev,
        const int* __restrict__ src, const int* __restrict__ dst,
        int* __restrict__ bcntD, int* __restrict__ bcntS,
        float* __restrict__ outp) {
    __shared__ int hD[NB], hS[NB];
    int bb = blockIdx.x;
    int tid = threadIdx.x;
    const int NC = NN * HID / 8 / 256;     // 6250 cast blocks

    if (bb < NC) {
        int t = bb * 256 + tid;
        const f32x4* pin = (const f32x4*)n_feat;
        f32x4 a = pin[2 * t], b = pin[2 * t + 1];
        u32x4 o;
        o[0] = (unsigned)f2bf(a[0]) | ((unsigned)f2bf(a[1]) << 16);
        o[1] = (unsigned)f2bf(a[2]) | ((unsigned)f2bf(a[3]) << 16);
        o[2] = (unsigned)f2bf(b[0]) | ((unsigned)f2bf(b[1]) << 16);
        o[3] = (unsigned)f2bf(b[2]) | ((unsigned)f2bf(b[3]) << 16);
        ((u32x4*)nfbf_u)[t] = o;
    } else if (bb < NC + 192) {
        int t = (bb - NC) * 256 + tid;
        int p = t >> 14, i = t & 16383;
        const float* Wsrc = (p == 0) ? WI : ((p == 1) ? WO : WS);
        float scale = (p == 2) ? (1.0f / 3.0f) : (2.0f / 3.0f);
        Wbf[t] = f2bf(Wsrc[i] * scale);
        if (t < HID) biasc[t] = (2.0f / 3.0f) * (bI[t] + bO[t]) + (1.0f / 3.0f) * bS[t];
    } else if (bb == NC + 192) {
        int cc = tid & 127;
        const float* e = (tid < 128) ? e_fwd : e_rev;
        float s = b_rel[cc];
        #pragma unroll 4
        for (int k = 0; k < HID; ++k) s += W_rel[cc * HID + k] * e[k];
        outp[(size_t)NN * HID + ((tid < 128) ? 0 : HID) + cc] = s;
    } else if (bb == NC + 193) {
        if (tid < 64) nfbf_u[(size_t)NN * 64 + tid] = 0;
    } else {
        for (int b = tid; b < NB; b += 256) { hD[b] = 0; hS[b] = 0; }
        __syncthreads();
        int base = (bb - NC - 194) * 8192;
        #pragma unroll
        for (int i = 0; i < 32; ++i) {
            int e = base + i * 256 + tid;
            if (e < NE) {
                atomicAdd(&hD[dst[e] >> 8], 1);
                atomicAdd(&hS[src[e] >> 8], 1);
            }
        }
        __syncthreads();
        for (int b = tid; b < NB; b += 256) {
            if (hD[b]) atomicAdd(&bcntD[b], hD[b]);
            if (hS[b]) atomicAdd(&bcntS[b], hS[b]);
        }
    }
}

// ---- scan bucket counts -> bases + cursors (one block, both dirs) ----
__global__ __launch_bounds__(512) void k_bucketscan(
        const int* __restrict__ bcntD, const int* __restrict__ bcntS,
        int* __restrict__ bbaseD, int* __restrict__ bbaseS,
        int* __restrict__ bcurD, int* __restrict__ bcurS) {
    __shared__ int wtot[8];
    int t = threadIdx.x, lane = t & 63, w = t >> 6;
    #pragma unroll
    for (int dir = 0; dir < 2; ++dir) {
        const int* cnt = dir ? bcntS : bcntD;
        int* bb = dir ? bbaseS : bbaseD;
        int* bc = dir ? bcurS : bcurD;
        int v = (t < NB) ? cnt[t] : 0;
        int x = v;
        #pragma unroll
        for (int off = 1; off < 64; off <<= 1) {
            int y = __shfl_up(x, off);
            if (lane >= off) x += y;
        }
        if (lane == 63) wtot[w] = x;
        __syncthreads();
        int wbase = 0;
        for (int j = 0; j < w; ++j) wbase += wtot[j];
        int incl = wbase + x;
        if (t < NB) { bb[t] = incl - v; bc[t] = incl - v; }
        if (t == NB - 1) bb[NB] = incl;
        __syncthreads();
    }
}

// ---- bin fill: scatter edges into bucket-contiguous packed arrays ----
__global__ __launch_bounds__(256) void k_binfill(
        const int* __restrict__ src, const int* __restrict__ dst,
        int* __restrict__ bcurD, int* __restrict__ bcurS,
        unsigned* __restrict__ binD, unsigned* __restrict__ binS) {
    __shared__ int hD[NB], hS[NB];
    int tid = threadIdx.x;
    for (int b = tid; b < NB; b += 256) { hD[b] = 0; hS[b] = 0; }
    __syncthreads();
    int base = blockIdx.x * 8192;
    int s[32], d[32];
    #pragma unroll
    for (int i = 0; i < 32; ++i) {
        int e = base + i * 256 + tid;
        s[i] = -1; d[i] = -1;
        if (e < NE) { s[i] = src[e]; d[i] = dst[e]; }
    }
    #pragma unroll
    for (int i = 0; i < 32; ++i) {
        if (s[i] >= 0) {
            atomicAdd(&hD[d[i] >> 8], 1);
            atomicAdd(&hS[s[i] >> 8], 1);
        }
    }
    __syncthreads();
    for (int b = tid; b < NB; b += 256) {
        int c = hD[b];
        hD[b] = c ? atomicAdd(&bcurD[b], c) : 0;
        c = hS[b];
        hS[b] = c ? atomicAdd(&bcurS[b], c) : 0;
    }
    __syncthreads();
    #pragma unroll
    for (int i = 0; i < 32; ++i) {
        if (s[i] >= 0) {
            int p = atomicAdd(&hD[d[i] >> 8], 1);
            binD[p] = ((unsigned)s[i] << 8) | ((unsigned)d[i] & 255u);
            int q = atomicAdd(&hS[s[i] >> 8], 1);
            binS[q] = ((unsigned)d[i] << 8) | ((unsigned)s[i] & 255u);
        }
    }
}

// ---- per-bucket counting sort -> packed col2 = (other<<4)|dloc + row_ptr ----
__global__ __launch_bounds__(256) void k_bucketsort(
        const unsigned* __restrict__ binD, const unsigned* __restrict__ binS,
        const int* __restrict__ bbaseD, const int* __restrict__ bbaseS,
        int* __restrict__ row_in, int* __restrict__ row_out,
        unsigned* __restrict__ col2_in, unsigned* __restrict__ col2_out) {
    __shared__ int c[256];
    __shared__ int wtot[4];
    int bid = blockIdx.x;
    int dir = (bid >= NB) ? 1 : 0;
    int b = dir ? (bid - NB) : bid;
    const unsigned* bin = dir ? binS : binD;
    const int* bb = dir ? bbaseS : bbaseD;
    int* row = dir ? row_out : row_in;
    unsigned* col2 = dir ? col2_out : col2_in;

    int tid = threadIdx.x, lane = tid & 63, w = tid >> 6;
    int base = bb[b], cnt = bb[b + 1] - base;
    int node0 = b << 8;
    int M = NN - node0; if (M > 256) M = 256;

    c[tid] = 0;
    __syncthreads();
    for (int k = tid; k < cnt; k += 256)
        atomicAdd(&c[bin[base + k] & 255u], 1);
    __syncthreads();
    int v = c[tid];
    int x = v;
    #pragma unroll
    for (int off = 1; off < 64; off <<= 1) {
        int y = __shfl_up(x, off);
        if (lane >= off) x += y;
    }
    if (lane == 63) wtot[w] = x;
    __syncthreads();
    int wbase = 0;
    for (int j = 0; j < w; ++j) wbase += wtot[j];
    int incl = wbase + x;
    if (tid < M) row[node0 + tid + 1] = base + incl;
    if (b == 0 && tid == 0) row[0] = 0;
    __syncthreads();
    c[tid] = base + incl - v;   // cursor = exclusive
    __syncthreads();
    for (int k = tid; k < cnt; k += 256) {
        unsigned pk = bin[base + k];
        int p = atomicAdd(&c[pk & 255u], 1);
        col2[p] = ((pk >> 8) << 4) | (pk & 15u);
    }
}

typedef __attribute__((address_space(3))) unsigned char as3u8;
typedef __attribute__((address_space(3))) unsigned as3u32;
typedef __attribute__((address_space(1))) const unsigned as1cu32;

// ---- fused aggregation + output GEMM, double-buffered 16-edge pipeline ----
// Two 4KB staging buffers per warp; counted vmcnt(5) in steady state so the
// next chunk's 4 row-loads stay in flight under the current chunk's compute.
// col2 prefetch (C) issued BEFORE staging loads (S) each iter so waiting on C
// never drains S (in-order vmcnt retirement).
__global__ __launch_bounds__(256) void k_agg(
        const unsigned char* __restrict__ nf,   // (NN+1) rows x 256 B bf16
        const float* __restrict__ e_fwd, const float* __restrict__ e_rev,
        const int* __restrict__ row_in, const unsigned* __restrict__ col2_in,
        const int* __restrict__ row_out, const unsigned* __restrict__ col2_out,
        const unsigned short* __restrict__ Wbf, const float* __restrict__ biasc,
        float* __restrict__ outp) {
    __shared__ __align__(1024) unsigned char smem[4][8192];
    int warp = threadIdx.x >> 6;
    int l = threadIdx.x & 63;
    int gbase = blockIdx.x * 2;
    int dir = warp & 1;
    int grp = gbase + (warp >> 1);
    int node0 = grp << 4;

    const int* row = dir ? row_out : row_in;
    const unsigned* col2 = dir ? col2_out : col2_in;
    const float* ev = dir ? e_rev : e_fwd;

    int lm = l & 15;
    int q = l >> 4;
    int kg = q * 8;
    int kslot = (l & 31) >> 1;

    as3u8* ldsp = (as3u8*)&smem[warp][0];
    as3u8* trp  = ldsp + (((q & 1) << 8) + (lm << 3));
    const unsigned SENT = ((unsigned)NN << 4);

    int ecur = row[node0];
    int eend = row[node0 + 16];

    f32x4 acc[8];
    #pragma unroll
    for (int nb = 0; nb < 8; ++nb) {
        acc[nb][0] = 0.0f; acc[nb][1] = 0.0f; acc[nb][2] = 0.0f; acc[nb][3] = 0.0f;
    }

#define STAGE(BUFOFF, PK) do { \
        int rowk_ = __shfl((int)((PK) >> 4), kslot); \
        const unsigned char* gp_ = nf + (((size_t)rowk_) << 8) + \
                                   ((l >> 5) << 5) + ((l & 1) << 4); \
        __builtin_amdgcn_global_load_lds((as1cu32*)(gp_ + 0),   (as3u32*)(ldsp + (BUFOFF) + 0),    16, 0, 0); \
        __builtin_amdgcn_global_load_lds((as1cu32*)(gp_ + 64),  (as3u32*)(ldsp + (BUFOFF) + 1024), 16, 0, 0); \
        __builtin_amdgcn_global_load_lds((as1cu32*)(gp_ + 128), (as3u32*)(ldsp + (BUFOFF) + 2048), 16, 0, 0); \
        __builtin_amdgcn_global_load_lds((as1cu32*)(gp_ + 192), (as3u32*)(ldsp + (BUFOFF) + 3072), 16, 0, 0); \
    } while (0)

#define COMPUTE(BUFOFF, AFRAG) do { \
        unsigned long long t0_[8], t1_[8]; \
        _Pragma("unroll") \
        for (int nb = 0; nb < 8; ++nb) { \
            asm volatile("ds_read_b64_tr_b16 %0, %1 offset:%2" \
                         : "=&v"(t0_[nb]) : "v"(trp + (BUFOFF)), "i"(nb * 512)); \
            asm volatile("ds_read_b64_tr_b16 %0, %1 offset:%2" \
                         : "=&v"(t1_[nb]) : "v"(trp + (BUFOFF)), "i"(nb * 512 + 128)); \
        } \
        asm volatile("s_waitcnt lgkmcnt(0)" ::: "memory"); \
        __builtin_amdgcn_sched_barrier(0); \
        _Pragma("unroll") \
        for (int nb = 0; nb < 8; ++nb) { \
            BP bp_; \
            bp_.u.lo = t0_[nb]; \
            bp_.u.hi = t1_[nb]; \
            acc[nb] = __builtin_amdgcn_mfma_f32_16x16x32_bf16((AFRAG).b, bp_.b, acc[nb], 0, 0, 0); \
        } \
    } while (0)

    if (ecur < eend) {
        // prologue: pk for chunk0, C_0 (pk for chunk1), S_0 into buf0
        unsigned pkA = (ecur + lm < eend) ? col2[ecur + lm] : SENT;
        unsigned pkB = SENT;
        if (ecur + 16 < eend)
            pkB = (ecur + 16 + lm < eend) ? col2[ecur + 16 + lm] : SENT;
        STAGE(0, pkA);
        int bp = 0;
        while (true) {
            int enext = ecur + 16;
            // A one-hot from pkA (lanes q>=2 -> zero)
            int dl = (int)(pkA & 15u);
            AW a;
            #pragma unroll
            for (int j2 = 0; j2 < 4; ++j2) {
                int d0 = __shfl(dl, kg + 2 * j2);
                int d1 = __shfl(dl, kg + 2 * j2 + 1);
                unsigned lo = (q < 2 && d0 == lm) ? 0x3F80u : 0u;
                unsigned hi = (q < 2 && d1 == lm) ? 0x3F80u : 0u;
                a.w[j2] = lo | (hi << 16);
            }
            if (enext < eend) {
                // C: prefetch pk for chunk j+2 (issued before S)
                unsigned pkC = SENT;
                if (enext + 16 < eend)
                    pkC = (enext + 16 + lm < eend) ? col2[enext + 16 + lm] : SENT;
                // S: stage chunk j+1 into the other buffer (uses pkB)
                STAGE((bp ^ 1) * 4096, pkB);
                // drain only chunk j's staging loads; C+S (5 ops) stay in flight
                asm volatile("s_waitcnt vmcnt(5)" ::: "memory");
                __builtin_amdgcn_sched_barrier(0);
                COMPUTE(bp * 4096, a);
                pkA = pkB; pkB = pkC; bp ^= 1; ecur = enext;
            } else {
                asm volatile("s_waitcnt vmcnt(0)" ::: "memory");
                __builtin_amdgcn_sched_barrier(0);
                COMPUTE(bp * 4096, a);
                break;
            }
        }
    }
#undef STAGE
#undef COMPUTE

    // ---- phase 2: scaled comp^T image -> LDS [feat*32 + node*2] (4KB) ----
    int rp = row[node0 + ((l < 17) ? l : 16)];
    int degi = __shfl(rp, l + 1) - rp;      // valid lanes 0..15
    float degfv = (float)degi;
    float rnv = (degi > 0) ? (1.0f / sqrtf(degfv)) : 1.0f;

    float evv[8];
    #pragma unroll
    for (int nb = 0; nb < 8; ++nb) evv[nb] = ev[nb * 16 + lm];

    #pragma unroll
    for (int ip = 0; ip < 2; ++ip) {
        int m0 = q * 4 + 2 * ip;
        float dm0 = __shfl(degfv, m0), rm0 = __shfl(rnv, m0);
        float dm1 = __shfl(degfv, m0 + 1), rm1 = __shfl(rnv, m0 + 1);
        #pragma unroll
        for (int nb = 0; nb < 8; ++nb) {
            float v0 = (acc[nb][2 * ip]     - dm0 * evv[nb]) * rm0;
            float v1 = (acc[nb][2 * ip + 1] - dm1 * evv[nb]) * rm1;
            unsigned dw = (unsigned)f2bf(v0) | ((unsigned)f2bf(v1) << 16);
            *(as3u32*)(ldsp + (nb * 16 + lm) * 32 + q * 8 + ip * 4) = dw;
        }
    }
    __syncthreads();

    // ---- phase 3: out^T = WI'@compf^T + WO'@compr^T + WS'@nf^T ----
    const unsigned short* nfu = (const unsigned short*)nf;
    int obase = warp * 2;                    // feat blocks 2w, 2w+1
    f32x4 D[2][2];
    #pragma unroll
    for (int a2 = 0; a2 < 2; ++a2)
        #pragma unroll
        for (int b2 = 0; b2 < 2; ++b2) {
            D[a2][b2][0] = 0.0f; D[a2][b2][1] = 0.0f;
            D[a2][b2][2] = 0.0f; D[a2][b2][3] = 0.0f;
        }

    #pragma unroll
    for (int p = 0; p < 3; ++p) {
        V8 A[2][4];
        #pragma unroll
        for (int ob2 = 0; ob2 < 2; ++ob2)
            #pragma unroll
            for (int kb = 0; kb < 4; ++kb)
                A[ob2][kb].s = *(const short8*)(Wbf + p * 16384 +
                    ((obase + ob2) * 16 + lm) * 128 + kb * 32 + q * 8);
        #pragma unroll
        for (int gg = 0; gg < 2; ++gg) {
            BP B[4];
            if (p < 2) {
                unsigned long long tb0[4], tb1[4];
                as3u8* ib = (as3u8*)&smem[gg * 2 + p][0] + ((lm << 3) + (q << 8));
                #pragma unroll
                for (int kb = 0; kb < 4; ++kb) {
                    asm volatile("ds_read_b64_tr_b16 %0, %1 offset:%2"
                                 : "=&v"(tb0[kb]) : "v"(ib), "i"(kb * 1024));
                    asm volatile("ds_read_b64_tr_b16 %0, %1 offset:%2"
                                 : "=&v"(tb1[kb]) : "v"(ib), "i"(kb * 1024 + 128));
                }
                asm volatile("s_waitcnt lgkmcnt(0)" ::: "memory");
                __builtin_amdgcn_sched_barrier(0);
                #pragma unroll
                for (int kb = 0; kb < 4; ++kb) { B[kb].u.lo = tb0[kb]; B[kb].u.hi = tb1[kb]; }
            } else {
                int node = (gbase + gg) * 16 + lm;
                #pragma unroll
                for (int kb = 0; kb < 4; ++kb)
                    B[kb].s = *(const short8*)(nfu + (size_t)node * 128 + kb * 32 + q * 8);
            }
            #pragma unroll
            for (int ob2 = 0; ob2 < 2; ++ob2)
                #pragma unroll
                for (int kb = 0; kb < 4; ++kb)
                    D[ob2][gg] = __builtin_amdgcn_mfma_f32_16x16x32_bf16(
                        A[ob2][kb].b, B[kb].b, D[ob2][gg], 0, 0, 0);
        }
    }

    // stores: out[node][o0..o0+3] = D + bias (coalesced 16B f32x4)
    #pragma unroll
    for (int ob2 = 0; ob2 < 2; ++ob2) {
        int o0 = (obase + ob2) * 16 + q * 4;
        f32x4 bias = *(const f32x4*)(biasc + o0);
        #pragma unroll
        for (int gg = 0; gg < 2; ++gg) {
            int node = (gbase + gg) * 16 + lm;
            f32x4 r = D[ob2][gg] + bias;
            *(f32x4*)(outp + (size_t)node * 128 + o0) = r;
        }
    }
}

extern "C" void kernel_launch(void* const* d_in, const int* in_sizes, int n_in,
                              void* d_out, int out_size, void* d_ws, size_t ws_size,
                              hipStream_t stream) {
    const float* n_feat = (const float*)d_in[0];
    const float* e_fwd  = (const float*)d_in[1];
    const float* e_rev  = (const float*)d_in[2];
    const float* W_I    = (const float*)d_in[3];
    const float* b_I    = (const float*)d_in[4];
    const float* W_O    = (const float*)d_in[5];
    const float* b_O    = (const float*)d_in[6];
    const float* W_S    = (const float*)d_in[7];
    const float* b_S    = (const float*)d_in[8];
    const float* W_rel  = (const float*)d_in[9];
    const float* b_rel  = (const float*)d_in[10];
    const int*   src    = (const int*)d_in[11];
    const int*   dst    = (const int*)d_in[12];
    float* outp = (float*)d_out;

    uint8_t* ws = (uint8_t*)d_ws;
    size_t off = 0;
    auto alloc = [&](size_t bytes) -> size_t {
        size_t r = off;
        off = (off + bytes + 255) & ~(size_t)255;
        return r;
    };
    size_t o_nfbf   = alloc((size_t)(NN + 1) * HID * 2);   // +1 zero row
    size_t o_wbf    = alloc((size_t)3 * HID * HID * 2);
    size_t o_biasc  = alloc(HID * 4);
    size_t o_rowin  = alloc((size_t)(NN + 1) * 4);
    size_t o_rowout = alloc((size_t)(NN + 1) * 4);
    size_t o_col2in = alloc((size_t)NE * 4);
    size_t o_col2out= alloc((size_t)NE * 4);
    size_t o_binD   = alloc((size_t)NE * 4);
    size_t o_binS   = alloc((size_t)NE * 4);
    size_t o_bcnt   = alloc((size_t)2 * NB * 4);
    size_t o_bbaseD = alloc((size_t)(NB + 1) * 4);
    size_t o_bbaseS = alloc((size_t)(NB + 1) * 4);
    size_t o_bcurD  = alloc((size_t)NB * 4);
    size_t o_bcurS  = alloc((size_t)NB * 4);
    (void)ws_size; (void)in_sizes; (void)n_in; (void)out_size;

    unsigned short* nfbf  = (unsigned short*)(ws + o_nfbf);
    unsigned short* wbf   = (unsigned short*)(ws + o_wbf);
    float*     biasc      = (float*)(ws + o_biasc);
    int* row_in  = (int*)(ws + o_rowin);
    int* row_out = (int*)(ws + o_rowout);
    unsigned* col2_in  = (unsigned*)(ws + o_col2in);
    unsigned* col2_out = (unsigned*)(ws + o_col2out);
    unsigned* binD = (unsigned*)(ws + o_binD);
    unsigned* binS = (unsigned*)(ws + o_binS);
    int* bcntD   = (int*)(ws + o_bcnt);
    int* bcntS   = bcntD + NB;
    int* bbaseD  = (int*)(ws + o_bbaseD);
    int* bbaseS  = (int*)(ws + o_bbaseS);
    int* bcurD   = (int*)(ws + o_bcurD);
    int* bcurS   = (int*)(ws + o_bcurS);

    (void)hipMemsetAsync(ws + o_bcnt, 0, (size_t)2 * NB * 4, stream);

    // fused prep: 6250 cast + 192 prepw + 1 evec + 1 zero-row + 123 bincount
    k_prep<<<6567, 256, 0, stream>>>(n_feat, (unsigned*)nfbf,
                                     W_I, W_O, W_S, b_I, b_O, b_S, wbf, biasc,
                                     W_rel, b_rel, e_fwd, e_rev,
                                     src, dst, bcntD, bcntS, outp);

    k_bucketscan<<<1, 512, 0, stream>>>(bcntD, bcntS, bbaseD, bbaseS, bcurD, bcurS);
    k_binfill<<<(NE + 8191) / 8192, 256, 0, stream>>>(src, dst, bcurD, bcurS, binD, binS);
    k_bucketsort<<<2 * NB, 256, 0, stream>>>(binD, binS, bbaseD, bbaseS,
                                             row_in, row_out, col2_in, col2_out);

    // fused agg+GEMM: 2 groups per block, 6250 groups -> 3125 blocks
    k_agg<<<3125, 256, 0, stream>>>((const unsigned char*)nfbf, e_fwd, e_rev,
                                    row_in, col2_in, row_out, col2_out,
                                    wbf, biasc, outp);
}

// Round 15
// 182.700 us; speedup vs baseline: 1.0670x; 1.0670x over previous
//
#include <hip/hip_runtime.h>
#include <stdint.h>

#define NN 100000
#define NE 1000000
#define HID 128
#define NB 391            // ceil(NN/256) buckets of 256 nodes

typedef __attribute__((ext_vector_type(4))) float f32x4;
typedef __attribute__((ext_vector_type(4))) unsigned u32x4;
typedef __attribute__((ext_vector_type(8))) short short8;
typedef __attribute__((ext_vector_type(8))) __bf16 bf16x8;

union V8 { short8 s; bf16x8 b; };
union AW { unsigned w[4]; bf16x8 b; };
union BP { struct { unsigned long long lo, hi; } u; short8 s; bf16x8 b; };

__device__ __forceinline__ unsigned short f2bf(float f) {
    unsigned u = __float_as_uint(f);
    unsigned r = u + 0x7fffu + ((u >> 16) & 1u);
    return (unsigned short)(r >> 16);
}

// ---- fused prep: cast | prepw | evec | zero-row | bincount, by blockIdx ----
__global__ __launch_bounds__(256) void k_prep(
        const float* __restrict__ n_feat, unsigned* __restrict__ nfbf_u,
        const float* __restrict__ WI, const float* __restrict__ WO,
        const float* __restrict__ WS, const float* __restrict__ bI,
        const float* __restrict__ bO, const float* __restrict__ bS,
        unsigned short* __restrict__ Wbf, float* __restrict__ biasc,
        const float* __restrict__ W_rel, const float* __restrict__ b_rel,
        const float* __restrict__ e_fwd, const float* __restrict__ e_rev,
        const int* __restrict__ src, const int* __restrict__ dst,
        int* __restrict__ bcntD, int* __restrict__ bcntS,
        float* __restrict__ outp) {
    __shared__ int hD[NB], hS[NB];
    int bb = blockIdx.x;
    int tid = threadIdx.x;
    const int NC = NN * HID / 8 / 256;     // 6250 cast blocks

    if (bb < NC) {
        int t = bb * 256 + tid;
        const f32x4* pin = (const f32x4*)n_feat;
        f32x4 a = pin[2 * t], b = pin[2 * t + 1];
        u32x4 o;
        o[0] = (unsigned)f2bf(a[0]) | ((unsigned)f2bf(a[1]) << 16);
        o[1] = (unsigned)f2bf(a[2]) | ((unsigned)f2bf(a[3]) << 16);
        o[2] = (unsigned)f2bf(b[0]) | ((unsigned)f2bf(b[1]) << 16);
        o[3] = (unsigned)f2bf(b[2]) | ((unsigned)f2bf(b[3]) << 16);
        ((u32x4*)nfbf_u)[t] = o;
    } else if (bb < NC + 192) {
        int t = (bb - NC) * 256 + tid;
        int p = t >> 14, i = t & 16383;
        const float* Wsrc = (p == 0) ? WI : ((p == 1) ? WO : WS);
        float scale = (p == 2) ? (1.0f / 3.0f) : (2.0f / 3.0f);
        Wbf[t] = f2bf(Wsrc[i] * scale);
        if (t < HID) biasc[t] = (2.0f / 3.0f) * (bI[t] + bO[t]) + (1.0f / 3.0f) * bS[t];
    } else if (bb == NC + 192) {
        int cc = tid & 127;
        const float* e = (tid < 128) ? e_fwd : e_rev;
        float s = b_rel[cc];
        #pragma unroll 4
        for (int k = 0; k < HID; ++k) s += W_rel[cc * HID + k] * e[k];
        outp[(size_t)NN * HID + ((tid < 128) ? 0 : HID) + cc] = s;
    } else if (bb == NC + 193) {
        if (tid < 64) nfbf_u[(size_t)NN * 64 + tid] = 0;
    } else {
        for (int b = tid; b < NB; b += 256) { hD[b] = 0; hS[b] = 0; }
        __syncthreads();
        int base = (bb - NC - 194) * 8192;
        #pragma unroll
        for (int i = 0; i < 32; ++i) {
            int e = base + i * 256 + tid;
            if (e < NE) {
                atomicAdd(&hD[dst[e] >> 8], 1);
                atomicAdd(&hS[src[e] >> 8], 1);
            }
        }
        __syncthreads();
        for (int b = tid; b < NB; b += 256) {
            if (hD[b]) atomicAdd(&bcntD[b], hD[b]);
            if (hS[b]) atomicAdd(&bcntS[b], hS[b]);
        }
    }
}

// ---- scan bucket counts -> bases + cursors (one block, both dirs) ----
__global__ __launch_bounds__(512) void k_bucketscan(
        const int* __restrict__ bcntD, const int* __restrict__ bcntS,
        int* __restrict__ bbaseD, int* __restrict__ bbaseS,
        int* __restrict__ bcurD, int* __restrict__ bcurS) {
    __shared__ int wtot[8];
    int t = threadIdx.x, lane = t & 63, w = t >> 6;
    #pragma unroll
    for (int dir = 0; dir < 2; ++dir) {
        const int* cnt = dir ? bcntS : bcntD;
        int* bb = dir ? bbaseS : bbaseD;
        int* bc = dir ? bcurS : bcurD;
        int v = (t < NB) ? cnt[t] : 0;
        int x = v;
        #pragma unroll
        for (int off = 1; off < 64; off <<= 1) {
            int y = __shfl_up(x, off);
            if (lane >= off) x += y;
        }
        if (lane == 63) wtot[w] = x;
        __syncthreads();
        int wbase = 0;
        for (int j = 0; j < w; ++j) wbase += wtot[j];
        int incl = wbase + x;
        if (t < NB) { bb[t] = incl - v; bc[t] = incl - v; }
        if (t == NB - 1) bb[NB] = incl;
        __syncthreads();
    }
}

// ---- bin fill: scatter edges into bucket-contiguous packed arrays ----
__global__ __launch_bounds__(256) void k_binfill(
        const int* __restrict__ src, const int* __restrict__ dst,
        int* __restrict__ bcurD, int* __restrict__ bcurS,
        unsigned* __restrict__ binD, unsigned* __restrict__ binS) {
    __shared__ int hD[NB], hS[NB];
    int tid = threadIdx.x;
    for (int b = tid; b < NB; b += 256) { hD[b] = 0; hS[b] = 0; }
    __syncthreads();
    int base = blockIdx.x * 8192;
    int s[32], d[32];
    #pragma unroll
    for (int i = 0; i < 32; ++i) {
        int e = base + i * 256 + tid;
        s[i] = -1; d[i] = -1;
        if (e < NE) { s[i] = src[e]; d[i] = dst[e]; }
    }
    #pragma unroll
    for (int i = 0; i < 32; ++i) {
        if (s[i] >= 0) {
            atomicAdd(&hD[d[i] >> 8], 1);
            atomicAdd(&hS[s[i] >> 8], 1);
        }
    }
    __syncthreads();
    for (int b = tid; b < NB; b += 256) {
        int c = hD[b];
        hD[b] = c ? atomicAdd(&bcurD[b], c) : 0;
        c = hS[b];
        hS[b] = c ? atomicAdd(&bcurS[b], c) : 0;
    }
    __syncthreads();
    #pragma unroll
    for (int i = 0; i < 32; ++i) {
        if (s[i] >= 0) {
            int p = atomicAdd(&hD[d[i] >> 8], 1);
            binD[p] = ((unsigned)s[i] << 8) | ((unsigned)d[i] & 255u);
            int q = atomicAdd(&hS[s[i] >> 8], 1);
            binS[q] = ((unsigned)d[i] << 8) | ((unsigned)s[i] & 255u);
        }
    }
}

// ---- per-bucket counting sort -> packed col2 = (other<<4)|dloc + row_ptr ----
__global__ __launch_bounds__(256) void k_bucketsort(
        const unsigned* __restrict__ binD, const unsigned* __restrict__ binS,
        const int* __restrict__ bbaseD, const int* __restrict__ bbaseS,
        int* __restrict__ row_in, int* __restrict__ row_out,
        unsigned* __restrict__ col2_in, unsigned* __restrict__ col2_out) {
    __shared__ int c[256];
    __shared__ int wtot[4];
    int bid = blockIdx.x;
    int dir = (bid >= NB) ? 1 : 0;
    int b = dir ? (bid - NB) : bid;
    const unsigned* bin = dir ? binS : binD;
    const int* bb = dir ? bbaseS : bbaseD;
    int* row = dir ? row_out : row_in;
    unsigned* col2 = dir ? col2_out : col2_in;

    int tid = threadIdx.x, lane = tid & 63, w = tid >> 6;
    int base = bb[b], cnt = bb[b + 1] - base;
    int node0 = b << 8;
    int M = NN - node0; if (M > 256) M = 256;

    c[tid] = 0;
    __syncthreads();
    for (int k = tid; k < cnt; k += 256)
        atomicAdd(&c[bin[base + k] & 255u], 1);
    __syncthreads();
    int v = c[tid];
    int x = v;
    #pragma unroll
    for (int off = 1; off < 64; off <<= 1) {
        int y = __shfl_up(x, off);
        if (lane >= off) x += y;
    }
    if (lane == 63) wtot[w] = x;
    __syncthreads();
    int wbase = 0;
    for (int j = 0; j < w; ++j) wbase += wtot[j];
    int incl = wbase + x;
    if (tid < M) row[node0 + tid + 1] = base + incl;
    if (b == 0 && tid == 0) row[0] = 0;
    __syncthreads();
    c[tid] = base + incl - v;   // cursor = exclusive
    __syncthreads();
    for (int k = tid; k < cnt; k += 256) {
        unsigned pk = bin[base + k];
        int p = atomicAdd(&c[pk & 255u], 1);
        col2[p] = ((pk >> 8) << 4) | (pk & 15u);
    }
}

typedef __attribute__((address_space(3))) unsigned char as3u8;
typedef __attribute__((address_space(3))) unsigned as3u32;
typedef __attribute__((address_space(1))) const unsigned as1cu32;

// ---- fused aggregation + output GEMM: 32-edge chunks, single-buffered ----
// (r12 geometry — the best measured — with packed col2 + 1-ahead prefetch)
// Staging [cb=8][k=32][16] = 8KB/warp: lane l -> row kslot=l>>1, half h=l&1;
// GLL I: src gp+I*32, dst ldsp+I*1024 (+16l HW). tr addr q*256+lm*8,
// offs nb*1024/+128 -> B[q*8+j][nb*16+lm].
__global__ __launch_bounds__(256) void k_agg(
        const unsigned char* __restrict__ nf,   // (NN+1) rows x 256 B bf16
        const float* __restrict__ e_fwd, const float* __restrict__ e_rev,
        const int* __restrict__ row_in, const unsigned* __restrict__ col2_in,
        const int* __restrict__ row_out, const unsigned* __restrict__ col2_out,
        const unsigned short* __restrict__ Wbf, const float* __restrict__ biasc,
        float* __restrict__ outp) {
    __shared__ __align__(1024) unsigned char smem[4][8192];
    int warp = threadIdx.x >> 6;
    int l = threadIdx.x & 63;
    int gbase = blockIdx.x * 2;
    int dir = warp & 1;
    int grp = gbase + (warp >> 1);
    int node0 = grp << 4;

    const int* row = dir ? row_out : row_in;
    const unsigned* col2 = dir ? col2_out : col2_in;
    const float* ev = dir ? e_rev : e_fwd;

    int lm = l & 15;
    int q = l >> 4;
    int kg = q * 8;
    int la = l & 31;
    int kslot = l >> 1;
    int h = l & 1;

    as3u8* ldsp = (as3u8*)&smem[warp][0];
    as3u8* trp  = ldsp + ((q << 8) + (lm << 3));
    const unsigned SENT = ((unsigned)NN << 4);

    int ecur = row[node0];
    int eend = row[node0 + 16];

    f32x4 acc[8];
    #pragma unroll
    for (int nb = 0; nb < 8; ++nb) {
        acc[nb][0] = 0.0f; acc[nb][1] = 0.0f; acc[nb][2] = 0.0f; acc[nb][3] = 0.0f;
    }

    // gather: 32-edge chunks, col2 prefetched one chunk ahead
    unsigned pk = (ecur + la < eend) ? col2[ecur + la] : SENT;
    while (ecur < eend) {
        int enext = ecur + 32;
        int rowk = __shfl((int)(pk >> 4), kslot);
        const unsigned char* gp = nf + (((size_t)rowk) << 8) + (h << 4);
#define GLL(I) __builtin_amdgcn_global_load_lds( \
            (as1cu32*)(gp + (I) * 32), \
            (as3u32*)(ldsp + (I) * 1024), 16, 0, 0)
        GLL(0); GLL(1); GLL(2); GLL(3); GLL(4); GLL(5); GLL(6); GLL(7);
#undef GLL
        unsigned pknext = (enext < eend)
            ? ((enext + la < eend) ? col2[enext + la] : SENT)
            : 0u;

        int dl = (int)(pk & 15u);
        AW a;
        #pragma unroll
        for (int j2 = 0; j2 < 4; ++j2) {
            int d0 = __shfl(dl, kg + 2 * j2);
            int d1 = __shfl(dl, kg + 2 * j2 + 1);
            unsigned lo = (d0 == lm) ? 0x3F80u : 0u;
            unsigned hi = (d1 == lm) ? 0x3F80u : 0u;
            a.w[j2] = lo | (hi << 16);
        }

        asm volatile("s_waitcnt vmcnt(0)" ::: "memory");
        __builtin_amdgcn_sched_barrier(0);

        unsigned long long t0[8], t1[8];
        #pragma unroll
        for (int nb = 0; nb < 8; ++nb) {
            asm volatile("ds_read_b64_tr_b16 %0, %1 offset:%2"
                         : "=&v"(t0[nb]) : "v"(trp), "i"(nb * 1024));
            asm volatile("ds_read_b64_tr_b16 %0, %1 offset:%2"
                         : "=&v"(t1[nb]) : "v"(trp), "i"(nb * 1024 + 128));
        }
        asm volatile("s_waitcnt lgkmcnt(0)" ::: "memory");
        __builtin_amdgcn_sched_barrier(0);

        #pragma unroll
        for (int nb = 0; nb < 8; ++nb) {
            BP bp;
            bp.u.lo = t0[nb];
            bp.u.hi = t1[nb];
            acc[nb] = __builtin_amdgcn_mfma_f32_16x16x32_bf16(a.b, bp.b, acc[nb], 0, 0, 0);
        }
        pk = pknext;
        ecur = enext;
    }

    // ---- phase 2: scaled comp^T image -> LDS [feat*32 + node*2] (4KB) ----
    int rp = row[node0 + ((l < 17) ? l : 16)];
    int degi = __shfl(rp, l + 1) - rp;      // valid lanes 0..15
    float degfv = (float)degi;
    float rnv = (degi > 0) ? (1.0f / sqrtf(degfv)) : 1.0f;

    float evv[8];
    #pragma unroll
    for (int nb = 0; nb < 8; ++nb) evv[nb] = ev[nb * 16 + lm];

    #pragma unroll
    for (int ip = 0; ip < 2; ++ip) {
        int m0 = q * 4 + 2 * ip;
        float dm0 = __shfl(degfv, m0), rm0 = __shfl(rnv, m0);
        float dm1 = __shfl(degfv, m0 + 1), rm1 = __shfl(rnv, m0 + 1);
        #pragma unroll
        for (int nb = 0; nb < 8; ++nb) {
            float v0 = (acc[nb][2 * ip]     - dm0 * evv[nb]) * rm0;
            float v1 = (acc[nb][2 * ip + 1] - dm1 * evv[nb]) * rm1;
            unsigned dw = (unsigned)f2bf(v0) | ((unsigned)f2bf(v1) << 16);
            *(as3u32*)(ldsp + (nb * 16 + lm) * 32 + q * 8 + ip * 4) = dw;
        }
    }
    __syncthreads();

    // ---- phase 3: out^T = WI'@compf^T + WO'@compr^T + WS'@nf^T ----
    const unsigned short* nfu = (const unsigned short*)nf;
    int obase = warp * 2;                    // feat blocks 2w, 2w+1
    f32x4 D[2][2];
    #pragma unroll
    for (int a2 = 0; a2 < 2; ++a2)
        #pragma unroll
        for (int b2 = 0; b2 < 2; ++b2) {
            D[a2][b2][0] = 0.0f; D[a2][b2][1] = 0.0f;
            D[a2][b2][2] = 0.0f; D[a2][b2][3] = 0.0f;
        }

    #pragma unroll
    for (int p = 0; p < 3; ++p) {
        V8 A[2][4];
        #pragma unroll
        for (int ob2 = 0; ob2 < 2; ++ob2)
            #pragma unroll
            for (int kb = 0; kb < 4; ++kb)
                A[ob2][kb].s = *(const short8*)(Wbf + p * 16384 +
                    ((obase + ob2) * 16 + lm) * 128 + kb * 32 + q * 8);
        #pragma unroll
        for (int gg = 0; gg < 2; ++gg) {
            BP B[4];
            if (p < 2) {
                unsigned long long tb0[4], tb1[4];
                as3u8* ib = (as3u8*)&smem[gg * 2 + p][0] + ((lm << 3) + (q << 8));
                #pragma unroll
                for (int kb = 0; kb < 4; ++kb) {
                    asm volatile("ds_read_b64_tr_b16 %0, %1 offset:%2"
                                 : "=&v"(tb0[kb]) : "v"(ib), "i"(kb * 1024));
                    asm volatile("ds_read_b64_tr_b16 %0, %1 offset:%2"
                                 : "=&v"(tb1[kb]) : "v"(ib), "i"(kb * 1024 + 128));
                }
                asm volatile("s_waitcnt lgkmcnt(0)" ::: "memory");
                __builtin_amdgcn_sched_barrier(0);
                #pragma unroll
                for (int kb = 0; kb < 4; ++kb) { B[kb].u.lo = tb0[kb]; B[kb].u.hi = tb1[kb]; }
            } else {
                int node = (gbase + gg) * 16 + lm;
                #pragma unroll
                for (int kb = 0; kb < 4; ++kb)
                    B[kb].s = *(const short8*)(nfu + (size_t)node * 128 + kb * 32 + q * 8);
            }
            #pragma unroll
            for (int ob2 = 0; ob2 < 2; ++ob2)
                #pragma unroll
                for (int kb = 0; kb < 4; ++kb)
                    D[ob2][gg] = __builtin_amdgcn_mfma_f32_16x16x32_bf16(
                        A[ob2][kb].b, B[kb].b, D[ob2][gg], 0, 0, 0);
        }
    }

    // stores: out[node][o0..o0+3] = D + bias (coalesced 16B f32x4)
    #pragma unroll
    for (int ob2 = 0; ob2 < 2; ++ob2) {
        int o0 = (obase + ob2) * 16 + q * 4;
        f32x4 bias = *(const f32x4*)(biasc + o0);
        #pragma unroll
        for (int gg = 0; gg < 2; ++gg) {
            int node = (gbase + gg) * 16 + lm;
            f32x4 r = D[ob2][gg] + bias;
            *(f32x4*)(outp + (size_t)node * 128 + o0) = r;
        }
    }
}

extern "C" void kernel_launch(void* const* d_in, const int* in_sizes, int n_in,
                              void* d_out, int out_size, void* d_ws, size_t ws_size,
                              hipStream_t stream) {
    const float* n_feat = (const float*)d_in[0];
    const float* e_fwd  = (const float*)d_in[1];
    const float* e_rev  = (const float*)d_in[2];
    const float* W_I    = (const float*)d_in[3];
    const float* b_I    = (const float*)d_in[4];
    const float* W_O    = (const float*)d_in[5];
    const float* b_O    = (const float*)d_in[6];
    const float* W_S    = (const float*)d_in[7];
    const float* b_S    = (const float*)d_in[8];
    const float* W_rel  = (const float*)d_in[9];
    const float* b_rel  = (const float*)d_in[10];
    const int*   src    = (const int*)d_in[11];
    const int*   dst    = (const int*)d_in[12];
    float* outp = (float*)d_out;

    uint8_t* ws = (uint8_t*)d_ws;
    size_t off = 0;
    auto alloc = [&](size_t bytes) -> size_t {
        size_t r = off;
        off = (off + bytes + 255) & ~(size_t)255;
        return r;
    };
    size_t o_nfbf   = alloc((size_t)(NN + 1) * HID * 2);   // +1 zero row
    size_t o_wbf    = alloc((size_t)3 * HID * HID * 2);
    size_t o_biasc  = alloc(HID * 4);
    size_t o_rowin  = alloc((size_t)(NN + 1) * 4);
    size_t o_rowout = alloc((size_t)(NN + 1) * 4);
    size_t o_col2in = alloc((size_t)NE * 4);
    size_t o_col2out= alloc((size_t)NE * 4);
    size_t o_binD   = alloc((size_t)NE * 4);
    size_t o_binS   = alloc((size_t)NE * 4);
    size_t o_bcnt   = alloc((size_t)2 * NB * 4);
    size_t o_bbaseD = alloc((size_t)(NB + 1) * 4);
    size_t o_bbaseS = alloc((size_t)(NB + 1) * 4);
    size_t o_bcurD  = alloc((size_t)NB * 4);
    size_t o_bcurS  = alloc((size_t)NB * 4);
    (void)ws_size; (void)in_sizes; (void)n_in; (void)out_size;

    unsigned short* nfbf  = (unsigned short*)(ws + o_nfbf);
    unsigned short* wbf   = (unsigned short*)(ws + o_wbf);
    float*     biasc      = (float*)(ws + o_biasc);
    int* row_in  = (int*)(ws + o_rowin);
    int* row_out = (int*)(ws + o_rowout);
    unsigned* col2_in  = (unsigned*)(ws + o_col2in);
    unsigned* col2_out = (unsigned*)(ws + o_col2out);
    unsigned* binD = (unsigned*)(ws + o_binD);
    unsigned* binS = (unsigned*)(ws + o_binS);
    int* bcntD   = (int*)(ws + o_bcnt);
    int* bcntS   = bcntD + NB;
    int* bbaseD  = (int*)(ws + o_bbaseD);
    int* bbaseS  = (int*)(ws + o_bbaseS);
    int* bcurD   = (int*)(ws + o_bcurD);
    int* bcurS   = (int*)(ws + o_bcurS);

    (void)hipMemsetAsync(ws + o_bcnt, 0, (size_t)2 * NB * 4, stream);

    // fused prep: 6250 cast + 192 prepw + 1 evec + 1 zero-row + 123 bincount
    k_prep<<<6567, 256, 0, stream>>>(n_feat, (unsigned*)nfbf,
                                     W_I, W_O, W_S, b_I, b_O, b_S, wbf, biasc,
                                     W_rel, b_rel, e_fwd, e_rev,
                                     src, dst, bcntD, bcntS, outp);

    k_bucketscan<<<1, 512, 0, stream>>>(bcntD, bcntS, bbaseD, bbaseS, bcurD, bcurS);
    k_binfill<<<(NE + 8191) / 8192, 256, 0, stream>>>(src, dst, bcurD, bcurS, binD, binS);
    k_bucketsort<<<2 * NB, 256, 0, stream>>>(binD, binS, bbaseD, bbaseS,
                                             row_in, row_out, col2_in, col2_out);

    // fused agg+GEMM: 2 groups per block, 6250 groups -> 3125 blocks
    k_agg<<<3125, 256, 0, stream>>>((const unsigned char*)nfbf, e_fwd, e_rev,
                                    row_in, col2_in, row_out, col2_out,
                                    wbf, biasc, outp);
}